// Round 9
// baseline (259.358 us; speedup 1.0000x reference)
//
#include <hip/hip_runtime.h>
#include <hip/hip_bf16.h>

// Problem constants
#define B_SZ   4096
#define OBS_N  128
#define HID    512
// tanh(x) = 1 - 2/(2^(x*2log2e)+1). We pre-scale all tanh-feeding weights and
// biases by TANH_SCALE at prep time so the fused epilogue needs no per-element
// v_mul, and the bias is folded into the MFMA accumulator init (no v_add).
#define TANH_SCALE 2.885390081777927f   // 2*log2(e)

// S-MAJOR q rows: r = s*4096 + b. Fused kernel: block = 64 rows (one s, 64 b's),
// 512 threads (8 waves), 3 hidden layers chained through a 64KB LDS buffer
// (XOR-swizzled chunks). Layers compute D = W·hs (out x batch).
// R19: P DISPATCH ELIMINATED. W0 is built as an augmented K=160 MFMA-tiled
// matrix (rows 0-127 = obs weights, 128-135 = acts weights, 136 = bias, rest
// 0, all pre-scaled). Fused phase 0 = 5-kc MFMA loop: kc0-3 B-frags read
// straight from obs_bf (global, L1/L2-hot, shared across all 8 waves and
// reused by 32 s-blocks), kc4 = the acts/1.0 aug fragment. acc starts 0.
// Removes gemm_dual + p/pv workspaces + phase0's 256B/thread P-fragment reads
// (~270MB L3 traffic) for +64 net MFMA/wave. 2 dispatches: prep | fused.
// Layer loop: distance-2 weight prefetch + PAIRED ac loads (R18: zero spill,
// VGPR 64+64AGPR = exactly the 128 budget). Distance-3 spills (R16) — never.
// L3 head split across all 8 waves (two LDS partial slabs summed at store).

typedef __bf16 bf16x8_t __attribute__((ext_vector_type(8)));
typedef float  f32x4_t  __attribute__((ext_vector_type(4)));

// input already scaled by TANH_SCALE (weights/bias pre-scaled at prep)
__device__ inline float fast_tanh_pre(float x) {
    float e = __builtin_amdgcn_exp2f(x);
    return fmaf(-2.f, __builtin_amdgcn_rcpf(e + 1.f), 1.f);
}

// hs element (row, col): chunk c = col/8, phys = (c&~7)|((c^(row&7))&7),
// offset row*512 + phys*8 + col%8.
__device__ inline int hs_off(int row, int col) {
    int c = col >> 3;
    int phys = (c & ~7) | ((c ^ (row & 7)) & 7);
    return row * 512 + phys * 8 + (col & 7);
}

// ---------------- combined prep ----------------
// Grid layout (10504 blocks):
//   [0,512)        obs -> bf16 (float4)
//   [512,5632)     w1t/w2t/w3t/vw1t/vw2t MFMA tiling (5 x 1024)
//   [5632,9728)    acts_bf table
//   [9728,10368)   w0ta + vw0ta augmented K=160 tiled (320 each)
//   [10368,10376)  bias_s (scaled fp32 biases)
//   [10376,10504)  nbias = 0 (float4)
__global__ __launch_bounds__(256) void prep_kernel(
    const float* __restrict__ obs, const int* __restrict__ category,
    const float* __restrict__ qw0, const float* __restrict__ qb0,
    const float* __restrict__ qw1, const float* __restrict__ qw2,
    const float* __restrict__ qw3,
    const float* __restrict__ vw0, const float* __restrict__ vb0,
    const float* __restrict__ vw1, const float* __restrict__ vw2,
    const float* __restrict__ qb1, const float* __restrict__ qb2,
    const float* __restrict__ vb1, const float* __restrict__ vb2,
    __hip_bfloat16* __restrict__ obs_bf,
    __hip_bfloat16* __restrict__ w1t, __hip_bfloat16* __restrict__ w2t,
    __hip_bfloat16* __restrict__ w3t,
    __hip_bfloat16* __restrict__ vw1t, __hip_bfloat16* __restrict__ vw2t,
    __hip_bfloat16* __restrict__ w0ta, __hip_bfloat16* __restrict__ vw0ta,
    __hip_bfloat16* __restrict__ acts_bf, float* __restrict__ bias_s,
    float* __restrict__ nbias)
{
    const int bid = blockIdx.x, tid = threadIdx.x;
    if (bid < 512) {           // obs -> bf16, 4 elems/thread (float4)
        int i = bid * 1024 + tid * 4;
        float4 v = *(const float4*)&obs[i];
        union { __hip_bfloat16 b[4]; uint2 u; } o;
        o.b[0] = __float2bfloat16(v.x);
        o.b[1] = __float2bfloat16(v.y);
        o.b[2] = __float2bfloat16(v.z);
        o.b[3] = __float2bfloat16(v.w);
        *(uint2*)&obs_bf[i] = o.u;
    } else if (bid < 5632) {   // (512,512) -> MFMA-tiled
        int job = (bid - 512) >> 10;             // 0..4
        const float* srcs[5] = {qw1, qw2, qw3, vw1, vw2};
        __hip_bfloat16* dsts[5] = {w1t, w2t, w3t, vw1t, vw2t};
        // qw1/qw2/vw1/vw2 feed tanh -> pre-scale; qw3 (job 2) is the raw head
        float sc = (job == 2) ? 1.0f : TANH_SCALE;
        int idx = ((bid - 512) & 1023) * 256 + tid;    // 0..262143
        int e    = idx & 7;
        int lane = (idx >> 3) & 63;
        int tile, kc;
        if (job == 2) {        // w3t keeps the old tile-major layout (L3 path)
            kc   = (idx >> 9) & 15;
            tile = idx >> 13;
        } else {               // kc-major: one kc's 4 j-frags contiguous (4KB)
            int jj = (idx >> 9) & 3;
            kc     = (idx >> 11) & 15;
            int g  = idx >> 15;
            tile = g * 4 + jj;
        }
        int k = kc * 32 + (lane >> 4) * 8 + e;
        int n = tile * 16 + (lane & 15);
        dsts[job][idx] = __float2bfloat16(srcs[job][k * 512 + n] * sc);
    } else if (bid < 9728) {   // acts_bf table, s-major bf16: acts_bf[(s*4096+b)*8+d]
        int t = (bid - 5632) * 256 + tid;
        int d = t & 7;
        int r = t >> 3;
        int b = r & 4095, s = r >> 12;
        int U = (s >> 3) + ((d < (s & 7)) ? 1 : 0);
        float a = 0.f;
        if (U > 0) {
            float w = 0.125f, cum = 0.f;
            for (int j = 0; j < U; ++j) {
                cum += (float)category[b * 32 + j * 8 + d] * w;
                if (j == U - 1) a = -1.f + cum + 0.5f * w;
                w *= 0.0625f;
            }
        }
        acts_bf[t] = __float2bfloat16(a);
    } else if (bid < 10368) {  // w0ta + vw0ta: augmented K=160, kc-major tiled
        int sub = bid - 9728;            // 0..639
        bool isv = sub >= 320;
        int idx = (isv ? sub - 320 : sub) * 256 + tid;   // 0..81919
        int e    = idx & 7;
        int lane = (idx >> 3) & 63;
        int j    = (idx >> 9) & 3;
        int kcw  = idx >> 11;            // 0..159 = w*5 + kc
        int k = (kcw % 5) * 32 + (lane >> 4) * 8 + e;    // 0..159
        int n = ((kcw / 5) * 4 + j) * 16 + (lane & 15);  // 0..511
        float v = 0.f;
        if (!isv) {
            if (k < 136) v = qw0[k * 512 + n];           // obs + acts rows
            else if (k == 136) v = qb0[n];               // bias row
            w0ta[idx] = __float2bfloat16(v * TANH_SCALE);
        } else {
            if (k < 128) v = vw0[k * 512 + n];           // obs rows only
            else if (k == 136) v = vb0[n];
            vw0ta[idx] = __float2bfloat16(v * TANH_SCALE);
        }
    } else if (bid < 10376) {  // scaled fp32 biases for layers 1/2: qb1|qb2|vb1|vb2
        int idx = (bid - 10368) * 256 + tid;    // 0..2047
        const float* srcs[4] = {qb1, qb2, vb1, vb2};
        bias_s[idx] = srcs[idx >> 9][idx & 511] * TANH_SCALE;
    } else {                   // nbias = 0, 4 elems/thread (float4)
        int i = (bid - 10376) * 1024 + tid * 4;
        float4 z = {0.f, 0.f, 0.f, 0.f};
        *(float4*)&nbias[i] = z;
    }
}

// ---------------- epilogue: tanh(acc) -> hs (XOR-swizzled) ----------------
// acc is pre-scaled by TANH_SCALE and already includes the bias (acc init /
// bias row of the augmented W0).
__device__ inline void epi_store(
    __hip_bfloat16* hs, f32x4_t acc[4][4],
    int n0w, int quad, int t)
{
    #pragma unroll
    for (int j = 0; j < 4; ++j) {
        const int oc0 = n0w + j * 16 + quad * 4;     // 4 consecutive out cols
        const int cbase = oc0 >> 3;
        const int sub = (quad & 1) * 4;
        #pragma unroll
        for (int rt = 0; rt < 4; ++rt) {
            const int row = rt * 16 + t;
            union { __hip_bfloat16 b[4]; uint2 v; } o;
            o.b[0] = __float2bfloat16(fast_tanh_pre(acc[rt][j][0]));
            o.b[1] = __float2bfloat16(fast_tanh_pre(acc[rt][j][1]));
            o.b[2] = __float2bfloat16(fast_tanh_pre(acc[rt][j][2]));
            o.b[3] = __float2bfloat16(fast_tanh_pre(acc[rt][j][3]));
            const int phys = (cbase & ~7) | ((cbase ^ (row & 7)) & 7);
            *(uint2*)&hs[row * 512 + phys * 8 + sub] = o.v;
        }
    }
}

// ---------------- fused MLP layer: hs(64x512) = tanh(hs @ W^T + bias) ----------------
// Distance-2 weight prefetch (kc-pair loop, slots wA/wB) + PAIRED ac loads
// (a0/a1 -> 8 MFMAs -> a2/a3 -> 8 MFMAs) — R18-verified zero-spill config.
// Distance-3 spills (R16: WRITE 428MB) — do NOT add a third slot.
// bias_s is PRE-SCALED fp32 bias, folded into acc init (MFMA C-in).
__device__ inline void mfma_layer(
    __hip_bfloat16* hs, const __hip_bfloat16* __restrict__ Wt,
    const float* __restrict__ bias_s, int w, int lane)
{
    const int quad = lane >> 4, t = lane & 15;
    const int n0w = w * 64;
    // kc-major weight tiling: wave w's block = 32768 elems; per kc the 4
    // j-frags sit at consecutive 1KB offsets.
    const __hip_bfloat16* Wl = Wt + (size_t)w * 32768 + (size_t)lane * 8;
    f32x4_t acc[4][4];   // [rt = batch tile][j = out tile]
    #pragma unroll
    for (int j = 0; j < 4; ++j) {
        const f32x4_t bv = *(const f32x4_t*)&bias_s[n0w + j * 16 + quad * 4];
        #pragma unroll
        for (int rt = 0; rt < 4; ++rt)
            acc[rt][j] = bv;
    }
    bf16x8_t wA[4], wB[4];
    #pragma unroll
    for (int j = 0; j < 4; ++j) {
        wA[j] = *(const bf16x8_t*)(Wl + (size_t)(0 * 4 + j) * 512);
        wB[j] = *(const bf16x8_t*)(Wl + (size_t)(1 * 4 + j) * 512);
    }

    for (int m = 0; m < 8; ++m) {          // kc = 2m (slot A), 2m+1 (slot B)
        {   // even kc
            const int kc = 2 * m;
            const int craw = kc * 4 + quad;
            const int phys = (craw & ~7) | ((craw ^ (t & 7)) & 7);
            const __hip_bfloat16* hrow = &hs[t * 512 + phys * 8];
            bf16x8_t a0 = *(const bf16x8_t*)(hrow);
            bf16x8_t a1 = *(const bf16x8_t*)(hrow + 8192);
            __builtin_amdgcn_s_setprio(1);
            #pragma unroll
            for (int j = 0; j < 4; ++j) {
                acc[0][j] = __builtin_amdgcn_mfma_f32_16x16x32_bf16(wA[j], a0, acc[0][j], 0, 0, 0);
                acc[1][j] = __builtin_amdgcn_mfma_f32_16x16x32_bf16(wA[j], a1, acc[1][j], 0, 0, 0);
            }
            bf16x8_t a2 = *(const bf16x8_t*)(hrow + 2 * 8192);
            bf16x8_t a3 = *(const bf16x8_t*)(hrow + 3 * 8192);
            #pragma unroll
            for (int j = 0; j < 4; ++j) {
                acc[2][j] = __builtin_amdgcn_mfma_f32_16x16x32_bf16(wA[j], a2, acc[2][j], 0, 0, 0);
                acc[3][j] = __builtin_amdgcn_mfma_f32_16x16x32_bf16(wA[j], a3, acc[3][j], 0, 0, 0);
            }
            __builtin_amdgcn_s_setprio(0);
            if (m < 7) {
                #pragma unroll
                for (int j = 0; j < 4; ++j)
                    wA[j] = *(const bf16x8_t*)(Wl + (size_t)((kc + 2) * 4 + j) * 512);
            }
        }
        {   // odd kc
            const int kc = 2 * m + 1;
            const int craw = kc * 4 + quad;
            const int phys = (craw & ~7) | ((craw ^ (t & 7)) & 7);
            const __hip_bfloat16* hrow = &hs[t * 512 + phys * 8];
            bf16x8_t a0 = *(const bf16x8_t*)(hrow);
            bf16x8_t a1 = *(const bf16x8_t*)(hrow + 8192);
            __builtin_amdgcn_s_setprio(1);
            #pragma unroll
            for (int j = 0; j < 4; ++j) {
                acc[0][j] = __builtin_amdgcn_mfma_f32_16x16x32_bf16(wB[j], a0, acc[0][j], 0, 0, 0);
                acc[1][j] = __builtin_amdgcn_mfma_f32_16x16x32_bf16(wB[j], a1, acc[1][j], 0, 0, 0);
            }
            bf16x8_t a2 = *(const bf16x8_t*)(hrow + 2 * 8192);
            bf16x8_t a3 = *(const bf16x8_t*)(hrow + 3 * 8192);
            #pragma unroll
            for (int j = 0; j < 4; ++j) {
                acc[2][j] = __builtin_amdgcn_mfma_f32_16x16x32_bf16(wB[j], a2, acc[2][j], 0, 0, 0);
                acc[3][j] = __builtin_amdgcn_mfma_f32_16x16x32_bf16(wB[j], a3, acc[3][j], 0, 0, 0);
            }
            __builtin_amdgcn_s_setprio(0);
            if (m < 7) {
                #pragma unroll
                for (int j = 0; j < 4; ++j)
                    wB[j] = *(const bf16x8_t*)(Wl + (size_t)((kc + 2) * 4 + j) * 512);
            }
        }
    }
    __syncthreads();   // all reads of hs complete
    epi_store(hs, acc, n0w, quad, t);
    __syncthreads();   // hs now holds the layer output
}

// ---------------- fused MLP kernel: q-blocks [0,2048), v-blocks [2048,2112) ----------------
__global__ __launch_bounds__(512, 4) void fused_kernel(
    const __hip_bfloat16* __restrict__ obs_bf, // (4096,128) bf16 row-major
    const __hip_bfloat16* __restrict__ acts_bf,// (131072,8) bf16 s-major
    const __hip_bfloat16* __restrict__ w0ta,   // aug K=160 tiled, pre-scaled
    const __hip_bfloat16* __restrict__ vw0ta,
    const __hip_bfloat16* __restrict__ w1t, const float* __restrict__ qb1s,
    const __hip_bfloat16* __restrict__ w2t, const float* __restrict__ qb2s,
    const __hip_bfloat16* __restrict__ w3t, const float* __restrict__ qb3,
    float* __restrict__ advout,
    const __hip_bfloat16* __restrict__ vw1t, const float* __restrict__ vb1s,
    const __hip_bfloat16* __restrict__ vw2t, const float* __restrict__ vb2s,
    const float* __restrict__ vw3, const float* __restrict__ vb3,
    float* __restrict__ vout)
{
    __shared__ __hip_bfloat16 hs[64 * 512];   // 64 KB
    const int bid = blockIdx.x;
    const int tid = threadIdx.x;
    const int w = tid >> 6, lane = tid & 63;
    const int quad = lane >> 4, t = lane & 15;
    const bool is_q = bid < 2048;
    const int s  = is_q ? (bid >> 6) : 0;
    const int mb = is_q ? (bid & 63) : (bid - 2048);
    const int n0w = w * 64;

    // ---- phase 0: D = W0a·[obs;acts;1] — 5-kc MFMA, B-frags from global ----
    {
        const __hip_bfloat16* W0 = is_q ? w0ta : vw0ta;
        // per-wave aug weight block: 5 kc x 4 j x 512
        const __hip_bfloat16* Wl = W0 + (size_t)w * 10240 + (size_t)lane * 8;
        // lane's obs element base: row = mb*64 + rt*16 + t, col = kc*32 + quad*8
        const __hip_bfloat16* ob = obs_bf + ((size_t)(mb * 64) + t) * 128 + quad * 8;
        f32x4_t acc[4][4] = {};   // bias rides the k=136 weight row
        bf16x8_t wA[4], wB[4];
        #pragma unroll
        for (int j = 0; j < 4; ++j) {
            wA[j] = *(const bf16x8_t*)(Wl + (size_t)(0 * 4 + j) * 512);
            wB[j] = *(const bf16x8_t*)(Wl + (size_t)(1 * 4 + j) * 512);
        }
        // kc 0..3: obs part (slotA: kc0,kc2 / slotB: kc1,kc3)
        #pragma unroll
        for (int m = 0; m < 2; ++m) {
            {   // even kc = 2m (slot A)
                const int kc = 2 * m;
                bf16x8_t a0 = *(const bf16x8_t*)(ob + 0 * 16 * 128 + kc * 32);
                bf16x8_t a1 = *(const bf16x8_t*)(ob + 1 * 16 * 128 + kc * 32);
                bf16x8_t a2 = *(const bf16x8_t*)(ob + 2 * 16 * 128 + kc * 32);
                bf16x8_t a3 = *(const bf16x8_t*)(ob + 3 * 16 * 128 + kc * 32);
                __builtin_amdgcn_s_setprio(1);
                #pragma unroll
                for (int j = 0; j < 4; ++j) {
                    acc[0][j] = __builtin_amdgcn_mfma_f32_16x16x32_bf16(wA[j], a0, acc[0][j], 0, 0, 0);
                    acc[1][j] = __builtin_amdgcn_mfma_f32_16x16x32_bf16(wA[j], a1, acc[1][j], 0, 0, 0);
                    acc[2][j] = __builtin_amdgcn_mfma_f32_16x16x32_bf16(wA[j], a2, acc[2][j], 0, 0, 0);
                    acc[3][j] = __builtin_amdgcn_mfma_f32_16x16x32_bf16(wA[j], a3, acc[3][j], 0, 0, 0);
                }
                __builtin_amdgcn_s_setprio(0);
                #pragma unroll
                for (int j = 0; j < 4; ++j)   // refill A <- kc+2 (2 or 4)
                    wA[j] = *(const bf16x8_t*)(Wl + (size_t)((kc + 2) * 4 + j) * 512);
            }
            {   // odd kc = 2m+1 (slot B)
                const int kc = 2 * m + 1;
                bf16x8_t a0 = *(const bf16x8_t*)(ob + 0 * 16 * 128 + kc * 32);
                bf16x8_t a1 = *(const bf16x8_t*)(ob + 1 * 16 * 128 + kc * 32);
                bf16x8_t a2 = *(const bf16x8_t*)(ob + 2 * 16 * 128 + kc * 32);
                bf16x8_t a3 = *(const bf16x8_t*)(ob + 3 * 16 * 128 + kc * 32);
                __builtin_amdgcn_s_setprio(1);
                #pragma unroll
                for (int j = 0; j < 4; ++j) {
                    acc[0][j] = __builtin_amdgcn_mfma_f32_16x16x32_bf16(wB[j], a0, acc[0][j], 0, 0, 0);
                    acc[1][j] = __builtin_amdgcn_mfma_f32_16x16x32_bf16(wB[j], a1, acc[1][j], 0, 0, 0);
                    acc[2][j] = __builtin_amdgcn_mfma_f32_16x16x32_bf16(wB[j], a2, acc[2][j], 0, 0, 0);
                    acc[3][j] = __builtin_amdgcn_mfma_f32_16x16x32_bf16(wB[j], a3, acc[3][j], 0, 0, 0);
                }
                __builtin_amdgcn_s_setprio(0);
                if (m == 0) {
                    #pragma unroll
                    for (int j = 0; j < 4; ++j)   // refill B <- kc3
                        wB[j] = *(const bf16x8_t*)(Wl + (size_t)(3 * 4 + j) * 512);
                }
            }
        }
        // kc 4: aug part (acts + 1.0 + bias row); wA holds kc4
        {
            bf16x8_t bfrag[4];
            #pragma unroll
            for (int rt = 0; rt < 4; ++rt) {
                union { bf16x8_t vec; unsigned short u[8]; } bu;
                #pragma unroll
                for (int i = 0; i < 8; ++i) bu.u[i] = 0;
                if (quad == 1) bu.u[0] = 0x3F80;   // bf16 1.0 (k=136)
                if (is_q && quad == 0) {           // k=128..135 = acts
                    const long r = (long)s * 4096 + mb * 64 + rt * 16 + t;
                    bu.vec = *(const bf16x8_t*)&acts_bf[r * 8];
                }
                bfrag[rt] = bu.vec;
            }
            __builtin_amdgcn_s_setprio(1);
            #pragma unroll
            for (int j = 0; j < 4; ++j)
                #pragma unroll
                for (int rt = 0; rt < 4; ++rt)
                    acc[rt][j] = __builtin_amdgcn_mfma_f32_16x16x32_bf16(wA[j], bfrag[rt], acc[rt][j], 0, 0, 0);
            __builtin_amdgcn_s_setprio(0);
        }
        epi_store(hs, acc, n0w, quad, t);
    }
    __syncthreads();

    // ---- layers 1 and 2 ----
    mfma_layer(hs, is_q ? w1t : vw1t, is_q ? qb1s : vb1s, w, lane);
    mfma_layer(hs, is_q ? w2t : vw2t, is_q ? qb2s : vb2s, w, lane);

    // ---- layer 3 ----
    if (is_q) {
        // diag slice: 64 rows x 16 cols. ALL 8 waves: w&3 picks the row group,
        // w>>2 picks the kc half (0-7 / 8-15); partials in two LDS slabs.
        f32x4_t acc = {};
        {
            const __hip_bfloat16* W3l = w3t + ((size_t)s * 16 * 64 + (size_t)lane) * 8;
            const int kc0 = (w >> 2) * 8;
            const int wrow = (w & 3) * 16 + t;
            #pragma unroll
            for (int kk = 0; kk < 8; ++kk) {
                const int kc = kc0 + kk;
                const int craw = kc * 4 + quad;
                const int phys = (craw & ~7) | ((craw ^ (t & 7)) & 7);
                bf16x8_t a = *(const bf16x8_t*)&hs[wrow * 512 + phys * 8];
                bf16x8_t bq = *(const bf16x8_t*)(W3l + (size_t)kc * 512);
                acc = __builtin_amdgcn_mfma_f32_16x16x32_bf16(a, bq, acc, 0, 0, 0);
            }
        }
        __syncthreads();   // L3 reads of hs done; hs reusable as fp32 staging
        float* hsf = (float*)hs;   // two 64x16 fp32 slabs: [0..1023] and [1024..2047]
        {
            const float add = (w < 4) ? qb3[s * 16 + t] : 0.f;   // bias once
            const int base = (w >> 2) * 1024;
            #pragma unroll
            for (int rr = 0; rr < 4; ++rr)
                hsf[base + ((w & 3) * 16 + quad * 4 + rr) * 16 + t] = acc[rr] + add;
        }
        __syncthreads();
        // coalesced store: thread -> (row = tid>>3, colpair = tid&7), 64B/row
        const int row = tid >> 3, cp = tid & 7;
        float2 lo = *(const float2*)&hsf[row * 16 + cp * 2];
        float2 hi = *(const float2*)&hsf[1024 + row * 16 + cp * 2];
        float2 v2 = {lo.x + hi.x, lo.y + hi.y};
        *(float2*)&advout[(size_t)(mb * 64 + row) * 512 + s * 16 + cp * 2] = v2;
    } else {
        // value head: row = tid>>3 (0..63), seg = tid&7 sums 64 elems
        const int row = tid >> 3, seg = tid & 7;
        float sum = 0.f;
        for (int k = seg * 64; k < seg * 64 + 64; ++k)
            sum += __bfloat162float(hs[hs_off(row, k)]) * vw3[k];
        sum += __shfl_xor(sum, 1);
        sum += __shfl_xor(sum, 2);
        sum += __shfl_xor(sum, 4);
        if (seg == 0) vout[mb * 64 + row] = sum + vb3[0];
    }
}

// ---------------- launch ----------------
extern "C" void kernel_launch(void* const* d_in, const int* in_sizes, int n_in,
                              void* d_out, int out_size, void* d_ws, size_t ws_size,
                              hipStream_t stream) {
    const float* obs      = (const float*)d_in[0];
    const int*   category = (const int*)d_in[1];
    const float* v_w0 = (const float*)d_in[2];
    const float* v_b0 = (const float*)d_in[3];
    const float* v_w1 = (const float*)d_in[4];
    const float* v_b1 = (const float*)d_in[5];
    const float* v_w2 = (const float*)d_in[6];
    const float* v_b2 = (const float*)d_in[7];
    const float* v_w3 = (const float*)d_in[8];
    const float* v_b3 = (const float*)d_in[9];
    const float* q_w0 = (const float*)d_in[10];
    const float* q_b0 = (const float*)d_in[11];
    const float* q_w1 = (const float*)d_in[12];
    const float* q_b1 = (const float*)d_in[13];
    const float* q_w2 = (const float*)d_in[14];
    const float* q_b2 = (const float*)d_in[15];
    const float* q_w3 = (const float*)d_in[16];
    const float* q_b3 = (const float*)d_in[17];

    char* ws = (char*)d_ws;
    __hip_bfloat16* obs_bf = (__hip_bfloat16*)(ws + 0);              // 1 MB
    __hip_bfloat16* w1t    = (__hip_bfloat16*)(ws + 1048576);        // (512,512) tiled
    __hip_bfloat16* w2t    = (__hip_bfloat16*)(ws + 1572864);
    __hip_bfloat16* w3t    = (__hip_bfloat16*)(ws + 2097152);
    __hip_bfloat16* vw1t   = (__hip_bfloat16*)(ws + 2621440);
    __hip_bfloat16* vw2t   = (__hip_bfloat16*)(ws + 3145728);
    __hip_bfloat16* w0ta   = (__hip_bfloat16*)(ws + 3670016);        // 160 KB aug
    __hip_bfloat16* vw0ta  = (__hip_bfloat16*)(ws + 3833856);        // 160 KB aug
    __hip_bfloat16* acts_bf= (__hip_bfloat16*)(ws + 3997696);        // (131072,8) bf16, 2 MB
    float*          bias_s = (float*)         (ws + 6094848);        // 4x512 scaled fp32, 8 KB

    float* out       = (float*)d_out;
    float* out_value = out;
    float* out_adv   = out + 4096;
    float* out_nbias = out + 4096 + (size_t)B_SZ * 512;

    // 1) all prep in one dispatch (incl. aug W0 build + bias scaling + nbias)
    prep_kernel<<<10504, 256, 0, stream>>>(
        obs, category, q_w0, q_b0, q_w1, q_w2, q_w3, v_w0, v_b0, v_w1, v_w2,
        q_b1, q_b2, v_b1, v_b2,
        obs_bf, w1t, w2t, w3t, vw1t, vw2t, w0ta, vw0ta,
        acts_bf, bias_s, out_nbias);

    // 2) fused q+v MLP (2048 q-blocks + 64 v-blocks), 512 threads
    fused_kernel<<<2112, 512, 0, stream>>>(
        obs_bf, acts_bf, w0ta, vw0ta,
        w1t, bias_s, w2t, bias_s + 512, w3t, q_b3, out_adv,
        vw1t, bias_s + 1024, vw2t, bias_s + 1536, v_w3, v_b3, out_value);
}

// Round 10
// 254.315 us; speedup vs baseline: 1.0198x; 1.0198x over previous
//
#include <hip/hip_runtime.h>
#include <hip/hip_bf16.h>

// Problem constants
#define B_SZ   4096
#define OBS_N  128
#define HID    512
// tanh(x) = 1 - 2/(2^(x*2log2e)+1). We pre-scale all tanh-feeding weights and
// biases by TANH_SCALE at prep time so the fused epilogue needs no per-element
// v_mul, and the bias is folded into the MFMA accumulator init (no v_add).
#define TANH_SCALE 2.885390081777927f   // 2*log2(e)

// S-MAJOR q rows: r = s*4096 + b. Fused kernel: block = 64 rows (one s, 64 b's),
// 512 threads (8 waves), 3 hidden layers chained through a 64KB LDS buffer
// (XOR-swizzled chunks). Layers compute D = W·hs (out x batch).
// R20: 2 dispatches kept (R19 proved removing gemm_dual saves ~27us of
// overhead) but phase 0 reworked to fix R19's fused regression (+35us:
// spill returned to 47MB + global-operand stalls). The block's 16KB obs
// tile is staged into a SEPARATE LDS region obs_t (XOR-swizzled like hs;
// staged via global_load_lds with PRE-SWIZZLED per-lane source addrs —
// both-sides-or-neither). Phase 0 is then structurally identical to
// mfma_layer: LDS B-frags (hs read pattern), PAIRED a-loads (R18 zero-spill
// shape), distance-2 weight slots. LDS 64->80KB/block: still 2 blocks/CU.
// Layer loop unchanged (R18 config). Distance-3 spills (R16) — never.
// L3 head split across all 8 waves (two LDS partial slabs summed at store).

typedef __bf16 bf16x8_t __attribute__((ext_vector_type(8)));
typedef float  f32x4_t  __attribute__((ext_vector_type(4)));

// input already scaled by TANH_SCALE (weights/bias pre-scaled at prep)
__device__ inline float fast_tanh_pre(float x) {
    float e = __builtin_amdgcn_exp2f(x);
    return fmaf(-2.f, __builtin_amdgcn_rcpf(e + 1.f), 1.f);
}

__device__ inline void gld_lds16(const void* g, void* l) {
    __builtin_amdgcn_global_load_lds(
        (const __attribute__((address_space(1))) void*)g,
        (__attribute__((address_space(3))) void*)l, 16, 0, 0);
}

// hs element (row, col): chunk c = col/8, phys = (c&~7)|((c^(row&7))&7),
// offset row*512 + phys*8 + col%8.
__device__ inline int hs_off(int row, int col) {
    int c = col >> 3;
    int phys = (c & ~7) | ((c ^ (row & 7)) & 7);
    return row * 512 + phys * 8 + (col & 7);
}

// ---------------- combined prep ----------------
// Grid layout (10504 blocks):
//   [0,512)        obs -> bf16 (float4)
//   [512,5632)     w1t/w2t/w3t/vw1t/vw2t MFMA tiling (5 x 1024)
//   [5632,9728)    acts_bf table
//   [9728,10368)   w0ta + vw0ta augmented K=160 tiled (320 each)
//   [10368,10376)  bias_s (scaled fp32 biases)
//   [10376,10504)  nbias = 0 (float4)
__global__ __launch_bounds__(256) void prep_kernel(
    const float* __restrict__ obs, const int* __restrict__ category,
    const float* __restrict__ qw0, const float* __restrict__ qb0,
    const float* __restrict__ qw1, const float* __restrict__ qw2,
    const float* __restrict__ qw3,
    const float* __restrict__ vw0, const float* __restrict__ vb0,
    const float* __restrict__ vw1, const float* __restrict__ vw2,
    const float* __restrict__ qb1, const float* __restrict__ qb2,
    const float* __restrict__ vb1, const float* __restrict__ vb2,
    __hip_bfloat16* __restrict__ obs_bf,
    __hip_bfloat16* __restrict__ w1t, __hip_bfloat16* __restrict__ w2t,
    __hip_bfloat16* __restrict__ w3t,
    __hip_bfloat16* __restrict__ vw1t, __hip_bfloat16* __restrict__ vw2t,
    __hip_bfloat16* __restrict__ w0ta, __hip_bfloat16* __restrict__ vw0ta,
    __hip_bfloat16* __restrict__ acts_bf, float* __restrict__ bias_s,
    float* __restrict__ nbias)
{
    const int bid = blockIdx.x, tid = threadIdx.x;
    if (bid < 512) {           // obs -> bf16, 4 elems/thread (float4)
        int i = bid * 1024 + tid * 4;
        float4 v = *(const float4*)&obs[i];
        union { __hip_bfloat16 b[4]; uint2 u; } o;
        o.b[0] = __float2bfloat16(v.x);
        o.b[1] = __float2bfloat16(v.y);
        o.b[2] = __float2bfloat16(v.z);
        o.b[3] = __float2bfloat16(v.w);
        *(uint2*)&obs_bf[i] = o.u;
    } else if (bid < 5632) {   // (512,512) -> MFMA-tiled
        int job = (bid - 512) >> 10;             // 0..4
        const float* srcs[5] = {qw1, qw2, qw3, vw1, vw2};
        __hip_bfloat16* dsts[5] = {w1t, w2t, w3t, vw1t, vw2t};
        // qw1/qw2/vw1/vw2 feed tanh -> pre-scale; qw3 (job 2) is the raw head
        float sc = (job == 2) ? 1.0f : TANH_SCALE;
        int idx = ((bid - 512) & 1023) * 256 + tid;    // 0..262143
        int e    = idx & 7;
        int lane = (idx >> 3) & 63;
        int tile, kc;
        if (job == 2) {        // w3t keeps the old tile-major layout (L3 path)
            kc   = (idx >> 9) & 15;
            tile = idx >> 13;
        } else {               // kc-major: one kc's 4 j-frags contiguous (4KB)
            int jj = (idx >> 9) & 3;
            kc     = (idx >> 11) & 15;
            int g  = idx >> 15;
            tile = g * 4 + jj;
        }
        int k = kc * 32 + (lane >> 4) * 8 + e;
        int n = tile * 16 + (lane & 15);
        dsts[job][idx] = __float2bfloat16(srcs[job][k * 512 + n] * sc);
    } else if (bid < 9728) {   // acts_bf table, s-major bf16: acts_bf[(s*4096+b)*8+d]
        int t = (bid - 5632) * 256 + tid;
        int d = t & 7;
        int r = t >> 3;
        int b = r & 4095, s = r >> 12;
        int U = (s >> 3) + ((d < (s & 7)) ? 1 : 0);
        float a = 0.f;
        if (U > 0) {
            float w = 0.125f, cum = 0.f;
            for (int j = 0; j < U; ++j) {
                cum += (float)category[b * 32 + j * 8 + d] * w;
                if (j == U - 1) a = -1.f + cum + 0.5f * w;
                w *= 0.0625f;
            }
        }
        acts_bf[t] = __float2bfloat16(a);
    } else if (bid < 10368) {  // w0ta + vw0ta: augmented K=160, kc-major tiled
        int sub = bid - 9728;            // 0..639
        bool isv = sub >= 320;
        int idx = (isv ? sub - 320 : sub) * 256 + tid;   // 0..81919
        int e    = idx & 7;
        int lane = (idx >> 3) & 63;
        int j    = (idx >> 9) & 3;
        int kcw  = idx >> 11;            // 0..159 = w*5 + kc
        int k = (kcw % 5) * 32 + (lane >> 4) * 8 + e;    // 0..159
        int n = ((kcw / 5) * 4 + j) * 16 + (lane & 15);  // 0..511
        float v = 0.f;
        if (!isv) {
            if (k < 136) v = qw0[k * 512 + n];           // obs + acts rows
            else if (k == 136) v = qb0[n];               // bias row
            w0ta[idx] = __float2bfloat16(v * TANH_SCALE);
        } else {
            if (k < 128) v = vw0[k * 512 + n];           // obs rows only
            else if (k == 136) v = vb0[n];
            vw0ta[idx] = __float2bfloat16(v * TANH_SCALE);
        }
    } else if (bid < 10376) {  // scaled fp32 biases for layers 1/2: qb1|qb2|vb1|vb2
        int idx = (bid - 10368) * 256 + tid;    // 0..2047
        const float* srcs[4] = {qb1, qb2, vb1, vb2};
        bias_s[idx] = srcs[idx >> 9][idx & 511] * TANH_SCALE;
    } else {                   // nbias = 0, 4 elems/thread (float4)
        int i = (bid - 10376) * 1024 + tid * 4;
        float4 z = {0.f, 0.f, 0.f, 0.f};
        *(float4*)&nbias[i] = z;
    }
}

// ---------------- epilogue: tanh(acc) -> hs (XOR-swizzled) ----------------
// acc is pre-scaled by TANH_SCALE and already includes the bias (acc init /
// bias row of the augmented W0).
__device__ inline void epi_store(
    __hip_bfloat16* hs, f32x4_t acc[4][4],
    int n0w, int quad, int t)
{
    #pragma unroll
    for (int j = 0; j < 4; ++j) {
        const int oc0 = n0w + j * 16 + quad * 4;     // 4 consecutive out cols
        const int cbase = oc0 >> 3;
        const int sub = (quad & 1) * 4;
        #pragma unroll
        for (int rt = 0; rt < 4; ++rt) {
            const int row = rt * 16 + t;
            union { __hip_bfloat16 b[4]; uint2 v; } o;
            o.b[0] = __float2bfloat16(fast_tanh_pre(acc[rt][j][0]));
            o.b[1] = __float2bfloat16(fast_tanh_pre(acc[rt][j][1]));
            o.b[2] = __float2bfloat16(fast_tanh_pre(acc[rt][j][2]));
            o.b[3] = __float2bfloat16(fast_tanh_pre(acc[rt][j][3]));
            const int phys = (cbase & ~7) | ((cbase ^ (row & 7)) & 7);
            *(uint2*)&hs[row * 512 + phys * 8 + sub] = o.v;
        }
    }
}

// ---------------- fused MLP layer: hs(64x512) = tanh(hs @ W^T + bias) ----------------
// Distance-2 weight prefetch (kc-pair loop, slots wA/wB) + PAIRED ac loads
// (a0/a1 -> 8 MFMAs -> a2/a3 -> 8 MFMAs) — R18-verified zero-spill config.
// Distance-3 spills (R16: WRITE 428MB) — do NOT add a third slot.
// bias_s is PRE-SCALED fp32 bias, folded into acc init (MFMA C-in).
__device__ inline void mfma_layer(
    __hip_bfloat16* hs, const __hip_bfloat16* __restrict__ Wt,
    const float* __restrict__ bias_s, int w, int lane)
{
    const int quad = lane >> 4, t = lane & 15;
    const int n0w = w * 64;
    // kc-major weight tiling: wave w's block = 32768 elems; per kc the 4
    // j-frags sit at consecutive 1KB offsets.
    const __hip_bfloat16* Wl = Wt + (size_t)w * 32768 + (size_t)lane * 8;
    f32x4_t acc[4][4];   // [rt = batch tile][j = out tile]
    #pragma unroll
    for (int j = 0; j < 4; ++j) {
        const f32x4_t bv = *(const f32x4_t*)&bias_s[n0w + j * 16 + quad * 4];
        #pragma unroll
        for (int rt = 0; rt < 4; ++rt)
            acc[rt][j] = bv;
    }
    bf16x8_t wA[4], wB[4];
    #pragma unroll
    for (int j = 0; j < 4; ++j) {
        wA[j] = *(const bf16x8_t*)(Wl + (size_t)(0 * 4 + j) * 512);
        wB[j] = *(const bf16x8_t*)(Wl + (size_t)(1 * 4 + j) * 512);
    }

    for (int m = 0; m < 8; ++m) {          // kc = 2m (slot A), 2m+1 (slot B)
        {   // even kc
            const int kc = 2 * m;
            const int craw = kc * 4 + quad;
            const int phys = (craw & ~7) | ((craw ^ (t & 7)) & 7);
            const __hip_bfloat16* hrow = &hs[t * 512 + phys * 8];
            bf16x8_t a0 = *(const bf16x8_t*)(hrow);
            bf16x8_t a1 = *(const bf16x8_t*)(hrow + 8192);
            __builtin_amdgcn_s_setprio(1);
            #pragma unroll
            for (int j = 0; j < 4; ++j) {
                acc[0][j] = __builtin_amdgcn_mfma_f32_16x16x32_bf16(wA[j], a0, acc[0][j], 0, 0, 0);
                acc[1][j] = __builtin_amdgcn_mfma_f32_16x16x32_bf16(wA[j], a1, acc[1][j], 0, 0, 0);
            }
            bf16x8_t a2 = *(const bf16x8_t*)(hrow + 2 * 8192);
            bf16x8_t a3 = *(const bf16x8_t*)(hrow + 3 * 8192);
            #pragma unroll
            for (int j = 0; j < 4; ++j) {
                acc[2][j] = __builtin_amdgcn_mfma_f32_16x16x32_bf16(wA[j], a2, acc[2][j], 0, 0, 0);
                acc[3][j] = __builtin_amdgcn_mfma_f32_16x16x32_bf16(wA[j], a3, acc[3][j], 0, 0, 0);
            }
            __builtin_amdgcn_s_setprio(0);
            if (m < 7) {
                #pragma unroll
                for (int j = 0; j < 4; ++j)
                    wA[j] = *(const bf16x8_t*)(Wl + (size_t)((kc + 2) * 4 + j) * 512);
            }
        }
        {   // odd kc
            const int kc = 2 * m + 1;
            const int craw = kc * 4 + quad;
            const int phys = (craw & ~7) | ((craw ^ (t & 7)) & 7);
            const __hip_bfloat16* hrow = &hs[t * 512 + phys * 8];
            bf16x8_t a0 = *(const bf16x8_t*)(hrow);
            bf16x8_t a1 = *(const bf16x8_t*)(hrow + 8192);
            __builtin_amdgcn_s_setprio(1);
            #pragma unroll
            for (int j = 0; j < 4; ++j) {
                acc[0][j] = __builtin_amdgcn_mfma_f32_16x16x32_bf16(wB[j], a0, acc[0][j], 0, 0, 0);
                acc[1][j] = __builtin_amdgcn_mfma_f32_16x16x32_bf16(wB[j], a1, acc[1][j], 0, 0, 0);
            }
            bf16x8_t a2 = *(const bf16x8_t*)(hrow + 2 * 8192);
            bf16x8_t a3 = *(const bf16x8_t*)(hrow + 3 * 8192);
            #pragma unroll
            for (int j = 0; j < 4; ++j) {
                acc[2][j] = __builtin_amdgcn_mfma_f32_16x16x32_bf16(wB[j], a2, acc[2][j], 0, 0, 0);
                acc[3][j] = __builtin_amdgcn_mfma_f32_16x16x32_bf16(wB[j], a3, acc[3][j], 0, 0, 0);
            }
            __builtin_amdgcn_s_setprio(0);
            if (m < 7) {
                #pragma unroll
                for (int j = 0; j < 4; ++j)
                    wB[j] = *(const bf16x8_t*)(Wl + (size_t)((kc + 2) * 4 + j) * 512);
            }
        }
    }
    __syncthreads();   // all reads of hs complete
    epi_store(hs, acc, n0w, quad, t);
    __syncthreads();   // hs now holds the layer output
}

// ---------------- fused MLP kernel: q-blocks [0,2048), v-blocks [2048,2112) ----------------
__global__ __launch_bounds__(512, 4) void fused_kernel(
    const __hip_bfloat16* __restrict__ obs_bf, // (4096,128) bf16 row-major
    const __hip_bfloat16* __restrict__ acts_bf,// (131072,8) bf16 s-major
    const __hip_bfloat16* __restrict__ w0ta,   // aug K=160 tiled, pre-scaled
    const __hip_bfloat16* __restrict__ vw0ta,
    const __hip_bfloat16* __restrict__ w1t, const float* __restrict__ qb1s,
    const __hip_bfloat16* __restrict__ w2t, const float* __restrict__ qb2s,
    const __hip_bfloat16* __restrict__ w3t, const float* __restrict__ qb3,
    float* __restrict__ advout,
    const __hip_bfloat16* __restrict__ vw1t, const float* __restrict__ vb1s,
    const __hip_bfloat16* __restrict__ vw2t, const float* __restrict__ vb2s,
    const float* __restrict__ vw3, const float* __restrict__ vb3,
    float* __restrict__ vout)
{
    __shared__ __hip_bfloat16 hs[64 * 512];     // 64 KB
    __shared__ __hip_bfloat16 obs_t[64 * 128];  // 16 KB XOR-swizzled obs tile
    const int bid = blockIdx.x;
    const int tid = threadIdx.x;
    const int w = tid >> 6, lane = tid & 63;
    const int quad = lane >> 4, t = lane & 15;
    const bool is_q = bid < 2048;
    const int s  = is_q ? (bid >> 6) : 0;
    const int mb = is_q ? (bid & 63) : (bid - 2048);
    const int n0w = w * 64;

    // ---- stage obs tile -> obs_t (swizzled): linear LDS dest, pre-swizzled
    //      global source (both-sides-or-neither). Wave w stages rows
    //      w*4..w*4+3 and w*4+32..35; (r+32)&7 == r&7 so same source chunk.
    {
        const int r0 = w * 4 + (lane >> 4);          // 0..31
        const int ph = lane & 15;                    // phys chunk in LDS
        const int c  = (ph & ~7) | ((ph ^ (r0 & 7)) & 7);   // logical chunk
        const __hip_bfloat16* g0 = obs_bf + ((size_t)(mb * 64 + r0)) * 128 + c * 8;
        gld_lds16(g0, &obs_t[(size_t)w * 512]);
        gld_lds16(g0 + 32 * 128, &obs_t[(size_t)(w * 4 + 32) * 128]);
    }
    __syncthreads();

    // ---- phase 0: D = W0a·[obs;acts;1] — 5-kc MFMA, B-frags from obs_t ----
    {
        const __hip_bfloat16* W0 = is_q ? w0ta : vw0ta;
        // per-wave aug weight block: 5 kc x 4 j x 512
        const __hip_bfloat16* Wl = W0 + (size_t)w * 10240 + (size_t)lane * 8;
        f32x4_t acc[4][4] = {};   // bias rides the k=136 weight row
        bf16x8_t wA[4], wB[4];
        #pragma unroll
        for (int j = 0; j < 4; ++j) {
            wA[j] = *(const bf16x8_t*)(Wl + (size_t)(0 * 4 + j) * 512);
            wB[j] = *(const bf16x8_t*)(Wl + (size_t)(1 * 4 + j) * 512);
        }
        // kc 0..3: obs part (slotA: kc0,kc2 / slotB: kc1,kc3), paired a-loads
        #pragma unroll
        for (int m = 0; m < 2; ++m) {
            {   // even kc = 2m (slot A)
                const int kc = 2 * m;
                const int craw = kc * 4 + quad;
                const int phys = (craw & ~7) | ((craw ^ (t & 7)) & 7);
                const __hip_bfloat16* orow = &obs_t[t * 128 + phys * 8];
                bf16x8_t a0 = *(const bf16x8_t*)(orow);
                bf16x8_t a1 = *(const bf16x8_t*)(orow + 2048);
                __builtin_amdgcn_s_setprio(1);
                #pragma unroll
                for (int j = 0; j < 4; ++j) {
                    acc[0][j] = __builtin_amdgcn_mfma_f32_16x16x32_bf16(wA[j], a0, acc[0][j], 0, 0, 0);
                    acc[1][j] = __builtin_amdgcn_mfma_f32_16x16x32_bf16(wA[j], a1, acc[1][j], 0, 0, 0);
                }
                bf16x8_t a2 = *(const bf16x8_t*)(orow + 2 * 2048);
                bf16x8_t a3 = *(const bf16x8_t*)(orow + 3 * 2048);
                #pragma unroll
                for (int j = 0; j < 4; ++j) {
                    acc[2][j] = __builtin_amdgcn_mfma_f32_16x16x32_bf16(wA[j], a2, acc[2][j], 0, 0, 0);
                    acc[3][j] = __builtin_amdgcn_mfma_f32_16x16x32_bf16(wA[j], a3, acc[3][j], 0, 0, 0);
                }
                __builtin_amdgcn_s_setprio(0);
                #pragma unroll
                for (int j = 0; j < 4; ++j)   // refill A <- kc+2 (2 or 4)
                    wA[j] = *(const bf16x8_t*)(Wl + (size_t)((kc + 2) * 4 + j) * 512);
            }
            {   // odd kc = 2m+1 (slot B)
                const int kc = 2 * m + 1;
                const int craw = kc * 4 + quad;
                const int phys = (craw & ~7) | ((craw ^ (t & 7)) & 7);
                const __hip_bfloat16* orow = &obs_t[t * 128 + phys * 8];
                bf16x8_t a0 = *(const bf16x8_t*)(orow);
                bf16x8_t a1 = *(const bf16x8_t*)(orow + 2048);
                __builtin_amdgcn_s_setprio(1);
                #pragma unroll
                for (int j = 0; j < 4; ++j) {
                    acc[0][j] = __builtin_amdgcn_mfma_f32_16x16x32_bf16(wB[j], a0, acc[0][j], 0, 0, 0);
                    acc[1][j] = __builtin_amdgcn_mfma_f32_16x16x32_bf16(wB[j], a1, acc[1][j], 0, 0, 0);
                }
                bf16x8_t a2 = *(const bf16x8_t*)(orow + 2 * 2048);
                bf16x8_t a3 = *(const bf16x8_t*)(orow + 3 * 2048);
                #pragma unroll
                for (int j = 0; j < 4; ++j) {
                    acc[2][j] = __builtin_amdgcn_mfma_f32_16x16x32_bf16(wB[j], a2, acc[2][j], 0, 0, 0);
                    acc[3][j] = __builtin_amdgcn_mfma_f32_16x16x32_bf16(wB[j], a3, acc[3][j], 0, 0, 0);
                }
                __builtin_amdgcn_s_setprio(0);
                if (m == 0) {
                    #pragma unroll
                    for (int j = 0; j < 4; ++j)   // refill B <- kc3
                        wB[j] = *(const bf16x8_t*)(Wl + (size_t)(3 * 4 + j) * 512);
                }
            }
        }
        // kc 4: aug part (acts + 1.0 + bias row); wA holds kc4
        {
            bf16x8_t bfrag[4];
            #pragma unroll
            for (int rt = 0; rt < 4; ++rt) {
                union { bf16x8_t vec; unsigned short u[8]; } bu;
                #pragma unroll
                for (int i = 0; i < 8; ++i) bu.u[i] = 0;
                if (quad == 1) bu.u[0] = 0x3F80;   // bf16 1.0 (k=136)
                if (is_q && quad == 0) {           // k=128..135 = acts
                    const long r = (long)s * 4096 + mb * 64 + rt * 16 + t;
                    bu.vec = *(const bf16x8_t*)&acts_bf[r * 8];
                }
                bfrag[rt] = bu.vec;
            }
            __builtin_amdgcn_s_setprio(1);
            #pragma unroll
            for (int j = 0; j < 4; ++j)
                #pragma unroll
                for (int rt = 0; rt < 4; ++rt)
                    acc[rt][j] = __builtin_amdgcn_mfma_f32_16x16x32_bf16(wA[j], bfrag[rt], acc[rt][j], 0, 0, 0);
            __builtin_amdgcn_s_setprio(0);
        }
        epi_store(hs, acc, n0w, quad, t);
    }
    __syncthreads();

    // ---- layers 1 and 2 ----
    mfma_layer(hs, is_q ? w1t : vw1t, is_q ? qb1s : vb1s, w, lane);
    mfma_layer(hs, is_q ? w2t : vw2t, is_q ? qb2s : vb2s, w, lane);

    // ---- layer 3 ----
    if (is_q) {
        // diag slice: 64 rows x 16 cols. ALL 8 waves: w&3 picks the row group,
        // w>>2 picks the kc half (0-7 / 8-15); partials in two LDS slabs.
        f32x4_t acc = {};
        {
            const __hip_bfloat16* W3l = w3t + ((size_t)s * 16 * 64 + (size_t)lane) * 8;
            const int kc0 = (w >> 2) * 8;
            const int wrow = (w & 3) * 16 + t;
            #pragma unroll
            for (int kk = 0; kk < 8; ++kk) {
                const int kc = kc0 + kk;
                const int craw = kc * 4 + quad;
                const int phys = (craw & ~7) | ((craw ^ (t & 7)) & 7);
                bf16x8_t a = *(const bf16x8_t*)&hs[wrow * 512 + phys * 8];
                bf16x8_t bq = *(const bf16x8_t*)(W3l + (size_t)kc * 512);
                acc = __builtin_amdgcn_mfma_f32_16x16x32_bf16(a, bq, acc, 0, 0, 0);
            }
        }
        __syncthreads();   // L3 reads of hs done; hs reusable as fp32 staging
        float* hsf = (float*)hs;   // two 64x16 fp32 slabs: [0..1023] and [1024..2047]
        {
            const float add = (w < 4) ? qb3[s * 16 + t] : 0.f;   // bias once
            const int base = (w >> 2) * 1024;
            #pragma unroll
            for (int rr = 0; rr < 4; ++rr)
                hsf[base + ((w & 3) * 16 + quad * 4 + rr) * 16 + t] = acc[rr] + add;
        }
        __syncthreads();
        // coalesced store: thread -> (row = tid>>3, colpair = tid&7), 64B/row
        const int row = tid >> 3, cp = tid & 7;
        float2 lo = *(const float2*)&hsf[row * 16 + cp * 2];
        float2 hi = *(const float2*)&hsf[1024 + row * 16 + cp * 2];
        float2 v2 = {lo.x + hi.x, lo.y + hi.y};
        *(float2*)&advout[(size_t)(mb * 64 + row) * 512 + s * 16 + cp * 2] = v2;
    } else {
        // value head: row = tid>>3 (0..63), seg = tid&7 sums 64 elems
        const int row = tid >> 3, seg = tid & 7;
        float sum = 0.f;
        for (int k = seg * 64; k < seg * 64 + 64; ++k)
            sum += __bfloat162float(hs[hs_off(row, k)]) * vw3[k];
        sum += __shfl_xor(sum, 1);
        sum += __shfl_xor(sum, 2);
        sum += __shfl_xor(sum, 4);
        if (seg == 0) vout[mb * 64 + row] = sum + vb3[0];
    }
}

// ---------------- launch ----------------
extern "C" void kernel_launch(void* const* d_in, const int* in_sizes, int n_in,
                              void* d_out, int out_size, void* d_ws, size_t ws_size,
                              hipStream_t stream) {
    const float* obs      = (const float*)d_in[0];
    const int*   category = (const int*)d_in[1];
    const float* v_w0 = (const float*)d_in[2];
    const float* v_b0 = (const float*)d_in[3];
    const float* v_w1 = (const float*)d_in[4];
    const float* v_b1 = (const float*)d_in[5];
    const float* v_w2 = (const float*)d_in[6];
    const float* v_b2 = (const float*)d_in[7];
    const float* v_w3 = (const float*)d_in[8];
    const float* v_b3 = (const float*)d_in[9];
    const float* q_w0 = (const float*)d_in[10];
    const float* q_b0 = (const float*)d_in[11];
    const float* q_w1 = (const float*)d_in[12];
    const float* q_b1 = (const float*)d_in[13];
    const float* q_w2 = (const float*)d_in[14];
    const float* q_b2 = (const float*)d_in[15];
    const float* q_w3 = (const float*)d_in[16];
    const float* q_b3 = (const float*)d_in[17];

    char* ws = (char*)d_ws;
    __hip_bfloat16* obs_bf = (__hip_bfloat16*)(ws + 0);              // 1 MB
    __hip_bfloat16* w1t    = (__hip_bfloat16*)(ws + 1048576);        // (512,512) tiled
    __hip_bfloat16* w2t    = (__hip_bfloat16*)(ws + 1572864);
    __hip_bfloat16* w3t    = (__hip_bfloat16*)(ws + 2097152);
    __hip_bfloat16* vw1t   = (__hip_bfloat16*)(ws + 2621440);
    __hip_bfloat16* vw2t   = (__hip_bfloat16*)(ws + 3145728);
    __hip_bfloat16* w0ta   = (__hip_bfloat16*)(ws + 3670016);        // 160 KB aug
    __hip_bfloat16* vw0ta  = (__hip_bfloat16*)(ws + 3833856);        // 160 KB aug
    __hip_bfloat16* acts_bf= (__hip_bfloat16*)(ws + 3997696);        // (131072,8) bf16, 2 MB
    float*          bias_s = (float*)         (ws + 6094848);        // 4x512 scaled fp32, 8 KB

    float* out       = (float*)d_out;
    float* out_value = out;
    float* out_adv   = out + 4096;
    float* out_nbias = out + 4096 + (size_t)B_SZ * 512;

    // 1) all prep in one dispatch (incl. aug W0 build + bias scaling + nbias)
    prep_kernel<<<10504, 256, 0, stream>>>(
        obs, category, q_w0, q_b0, q_w1, q_w2, q_w3, v_w0, v_b0, v_w1, v_w2,
        q_b1, q_b2, v_b1, v_b2,
        obs_bf, w1t, w2t, w3t, vw1t, vw2t, w0ta, vw0ta,
        acts_bf, bias_s, out_nbias);

    // 2) fused q+v MLP (2048 q-blocks + 64 v-blocks), 512 threads
    fused_kernel<<<2112, 512, 0, stream>>>(
        obs_bf, acts_bf, w0ta, vw0ta,
        w1t, bias_s, w2t, bias_s + 512, w3t, q_b3, out_adv,
        vw1t, bias_s + 1024, vw2t, bias_s + 1536, v_w3, v_b3, out_value);
}